// Round 5
// baseline (216.892 us; speedup 1.0000x reference)
//
#include <hip/hip_runtime.h>
#include <hip/hip_bf16.h>

#define NSP 2304   // 48*48 spatial
#define NB  4      // batch

typedef unsigned short u16;
typedef __attribute__((ext_vector_type(8))) short short8;
typedef __attribute__((ext_vector_type(4))) float f32x4;
typedef __attribute__((ext_vector_type(4))) unsigned short u16x4;

// scale * log2(e), folded into Q at QKV-GEMM epilogue: softmax p = exp2(S)
#define K1S 0.25508040852656425f

static __device__ inline u16 f2bf(float f) {
  return __builtin_bit_cast(unsigned short, __float2bfloat16(f));
}

// ---------------------------------------------------------------------------
// prep 1: w_qkv (768*256) and w_out (256*256) fp32 -> bf16, one region.
// ---------------------------------------------------------------------------
__global__ __launch_bounds__(256) void convert_w(
    const float* __restrict__ wq, const float* __restrict__ wo,
    u16* __restrict__ dst) {
  int i = (blockIdx.x * 256 + threadIdx.x) * 4;
  float4 v;
  if (i < 196608) v = *(const float4*)(wq + i);
  else            v = *(const float4*)(wo + (i - 196608));
  u16x4 p = {f2bf(v.x), f2bf(v.y), f2bf(v.z), f2bf(v.w)};
  *(u16x4*)(dst + i) = p;
}

// ---------------------------------------------------------------------------
// prep 2: x fp32 [b][256][2304] -> xT bf16 [b][2304][256]
// ---------------------------------------------------------------------------
__global__ __launch_bounds__(256) void transpose_x(
    const float* __restrict__ x, u16* __restrict__ xT) {
  __shared__ float tile[32][33];
  const int t = threadIdx.x;
  const int n0 = blockIdx.x * 32, c0 = blockIdx.y * 32, b = blockIdx.z;
  const float* xb = x + ((size_t)b * 256 + c0) * NSP + n0;
#pragma unroll
  for (int e = t; e < 1024; e += 256) {
    int cc = e >> 5, nn = e & 31;
    tile[cc][nn] = xb[(size_t)cc * NSP + nn];
  }
  __syncthreads();
  u16* xTb = xT + ((size_t)b * NSP + n0) * 256 + c0;
#pragma unroll
  for (int e = t; e < 1024; e += 256) {
    int nn = e >> 5, cc = e & 31;
    xTb[(size_t)nn * 256 + cc] = f2bf(tile[cc][nn]);
  }
}

// ---------------------------------------------------------------------------
// bf16 MFMA GEMM, LDS-FREE (fragments straight from L2), no barriers.
// D = A (M x 256) * B[b] (N x 256)^T, 64x64 tile, 4 waves (2x2 of 32x32).
// EPI 0 (QKV): rows <256 (q, pre-scaled by K1S) and 256..511 (k)
//                -> qkT[b][n][512] transposed bf16;
//              rows >= 512 (v) -> vbuf[b][256][2304] natural bf16.
// EPI 1 (OUT): fp32 out[b][256][2304] + bias.
// ---------------------------------------------------------------------------
template <int EPI>
__global__ __launch_bounds__(256) void gemm_mfma(
    const u16* __restrict__ A, const u16* __restrict__ B,
    u16* __restrict__ qkT, u16* __restrict__ vbuf,
    float* __restrict__ outf, const float* __restrict__ bias, int N) {
  const int t = threadIdx.x, lane = t & 63, wid = t >> 6;
  const int lo = lane & 15, g = lane >> 4;
  const int wr = wid >> 1, wc = wid & 1;
  const int row0 = blockIdx.y * 64, col0 = blockIdx.x * 64, b = blockIdx.z;

  const u16* Ar = A + (size_t)(row0 + wr * 32 + lo) * 256 + g * 8;
  const u16* Br = B + ((size_t)b * N + col0 + wc * 32 + lo) * 256 + g * 8;

  f32x4 acc[2][2];
#pragma unroll
  for (int i = 0; i < 2; ++i)
#pragma unroll
    for (int j = 0; j < 2; ++j) acc[i][j] = (f32x4){0, 0, 0, 0};

#pragma unroll
  for (int kk = 0; kk < 8; ++kk) {
    const int kc = kk * 32;
    short8 a0 = *(const short8*)(Ar + kc);
    short8 a1 = *(const short8*)(Ar + 16 * 256 + kc);
    short8 b0 = *(const short8*)(Br + kc);
    short8 b1 = *(const short8*)(Br + 16 * 256 + kc);
    acc[0][0] = __builtin_amdgcn_mfma_f32_16x16x32_bf16(a0, b0, acc[0][0], 0, 0, 0);
    acc[0][1] = __builtin_amdgcn_mfma_f32_16x16x32_bf16(a0, b1, acc[0][1], 0, 0, 0);
    acc[1][0] = __builtin_amdgcn_mfma_f32_16x16x32_bf16(a1, b0, acc[1][0], 0, 0, 0);
    acc[1][1] = __builtin_amdgcn_mfma_f32_16x16x32_bf16(a1, b1, acc[1][1], 0, 0, 0);
  }

  const float qs = (EPI == 0 && row0 < 256) ? K1S : 1.0f;
#pragma unroll
  for (int m2 = 0; m2 < 2; ++m2)
#pragma unroll
    for (int n2 = 0; n2 < 2; ++n2) {
      int m = row0 + wr * 32 + m2 * 16 + g * 4;
      int n = col0 + wc * 32 + n2 * 16 + lo;
      if constexpr (EPI == 0) {
        if (row0 < 512) {  // q,k -> transposed qkT[b][n][m..m+3]
          u16x4 pk = {f2bf(acc[m2][n2][0] * qs), f2bf(acc[m2][n2][1] * qs),
                      f2bf(acc[m2][n2][2] * qs), f2bf(acc[m2][n2][3] * qs)};
          *(u16x4*)(qkT + ((size_t)b * NSP + n) * 512 + m) = pk;
        } else {           // v -> natural vbuf[b][m-512][n]
#pragma unroll
          for (int r = 0; r < 4; ++r)
            vbuf[((size_t)b * 256 + (m - 512 + r)) * NSP + n] =
                f2bf(acc[m2][n2][r]);
        }
      } else {
#pragma unroll
        for (int r = 0; r < 4; ++r)
          outf[((size_t)b * 256 + m + r) * NSP + n] =
              acc[m2][n2][r] + bias[m + r];
      }
    }
}

// ---------------------------------------------------------------------------
// MFMA flash attention, ZERO barriers, LDS only for per-wave P.
// Softmax: p = exp2(S) (scale·log2e pre-folded into Q; uniform offset cancels
// in o/l). Row-sum l computed by MFMA with ones as B-operand (lands in the
// same C/D row layout as the PV accumulators -> no cross-lane reduce).
// K/V fragments loaded directly from L2-resident qkT/vbuf each strip.
// ---------------------------------------------------------------------------
__global__ __launch_bounds__(256) void attn_mfma(
    const u16* __restrict__ qkT, const u16* __restrict__ vbuf,
    u16* __restrict__ attnoT) {
  const int it = blockIdx.x, h = blockIdx.y, b = blockIdx.z;
  const int t = threadIdx.x, lane = t & 63, wq = t >> 6;
  const int lo = lane & 15, g = lane >> 4;
  const int i0 = it * 64;

  const u16* qkTb = qkT + (size_t)b * NSP * 512;
  const u16* vb   = vbuf + ((size_t)b * 256 + h * 32) * NSP;
  u16* ob = attnoT + ((size_t)b * NSP + i0) * 256 + h * 32;

  __shared__ u16 Ps[4][16][68];   // per-wave P [query i][key j], stride 68

  // Q fragment (pre-scaled by K1S in the QKV GEMM)
  short8 qf = *(const short8*)(qkTb + (size_t)(i0 + wq * 16 + lo) * 512 +
                               h * 32 + g * 8);

  // direct-global fragment bases
  const u16* ksrc  = qkTb + (size_t)lo * 512 + 256 + h * 32 + g * 8;  // + j*512
  const u16* vsrc0 = vb + (size_t)lo * NSP + g * 8;                   // + j
  const u16* vsrc1 = vb + (size_t)(16 + lo) * NSP + g * 8;

  short8 ones;
#pragma unroll
  for (int e = 0; e < 8; ++e) ones[e] = (short)0x3F80;  // bf16 1.0

  f32x4 acc0 = {0, 0, 0, 0}, acc1 = {0, 0, 0, 0}, accl = {0, 0, 0, 0};

  for (int s = 0; s < 36; ++s) {
    const int j0 = s * 64;
    // ---- K fragments (4 x b128 from L2) ----
    short8 kf0 = *(const short8*)(ksrc + (size_t)(j0)      * 512);
    short8 kf1 = *(const short8*)(ksrc + (size_t)(j0 + 16) * 512);
    short8 kf2 = *(const short8*)(ksrc + (size_t)(j0 + 32) * 512);
    short8 kf3 = *(const short8*)(ksrc + (size_t)(j0 + 48) * 512);
    // ---- V fragments ----
    short8 vf00 = *(const short8*)(vsrc0 + j0);
    short8 vf01 = *(const short8*)(vsrc0 + j0 + 32);
    short8 vf10 = *(const short8*)(vsrc1 + j0);
    short8 vf11 = *(const short8*)(vsrc1 + j0 + 32);

    // ---- S = Q K^T ----
    f32x4 sv[4];
    sv[0] = __builtin_amdgcn_mfma_f32_16x16x32_bf16(qf, kf0, (f32x4){0,0,0,0}, 0, 0, 0);
    sv[1] = __builtin_amdgcn_mfma_f32_16x16x32_bf16(qf, kf1, (f32x4){0,0,0,0}, 0, 0, 0);
    sv[2] = __builtin_amdgcn_mfma_f32_16x16x32_bf16(qf, kf2, (f32x4){0,0,0,0}, 0, 0, 0);
    sv[3] = __builtin_amdgcn_mfma_f32_16x16x32_bf16(qf, kf3, (f32x4){0,0,0,0}, 0, 0, 0);

    // ---- p = exp2(S); write P to per-wave LDS ----
#pragma unroll
    for (int jt = 0; jt < 4; ++jt)
#pragma unroll
      for (int r = 0; r < 4; ++r)
        Ps[wq][g * 4 + r][jt * 16 + lo] =
            f2bf(__builtin_amdgcn_exp2f(sv[jt][r]));

    // ---- PV + row-sum (both via MFMA) ----
    short8 pf0 = *(const short8*)&Ps[wq][lo][g * 8];
    short8 pf1 = *(const short8*)&Ps[wq][lo][32 + g * 8];
    acc0 = __builtin_amdgcn_mfma_f32_16x16x32_bf16(pf0, vf00, acc0, 0, 0, 0);
    acc1 = __builtin_amdgcn_mfma_f32_16x16x32_bf16(pf0, vf10, acc1, 0, 0, 0);
    accl = __builtin_amdgcn_mfma_f32_16x16x32_bf16(pf0, ones, accl, 0, 0, 0);
    acc0 = __builtin_amdgcn_mfma_f32_16x16x32_bf16(pf1, vf01, acc0, 0, 0, 0);
    acc1 = __builtin_amdgcn_mfma_f32_16x16x32_bf16(pf1, vf11, acc1, 0, 0, 0);
    accl = __builtin_amdgcn_mfma_f32_16x16x32_bf16(pf1, ones, accl, 0, 0, 0);
  }

  // ---- normalize + bf16 store to attnoT[n][c] ----
#pragma unroll
  for (int r = 0; r < 4; ++r) {
    float inv = 1.0f / accl[r];
    int row = wq * 16 + g * 4 + r;
    ob[(size_t)row * 256 + lo]      = f2bf(acc0[r] * inv);
    ob[(size_t)row * 256 + 16 + lo] = f2bf(acc1[r] * inv);
  }
}

// ---------------------------------------------------------------------------
extern "C" void kernel_launch(void* const* d_in, const int* in_sizes, int n_in,
                              void* d_out, int out_size, void* d_ws, size_t ws_size,
                              hipStream_t stream) {
  const float* x     = (const float*)d_in[0];  // [4][256][48][48]
  const float* w_qkv = (const float*)d_in[1];  // [768][256]
  const float* w_out = (const float*)d_in[2];  // [256][256]
  const float* b_out = (const float*)d_in[3];  // [256]
  float* out = (float*)d_out;                  // [4][256][2304]

  u16* wbf    = (u16*)d_ws;                    // wqkv 196608 then wout 65536
  u16* xT     = wbf + 262144;                  // [4][2304][256]
  u16* qkT    = xT + (size_t)NB * NSP * 256;   // [4][2304][512]
  u16* vbuf   = qkT + (size_t)NB * NSP * 512;  // [4][256][2304]
  u16* attnoT = vbuf + (size_t)NB * 256 * NSP; // [4][2304][256]

  dim3 blk(256);
  convert_w<<<256, blk, 0, stream>>>(w_qkv, w_out, wbf);
  transpose_x<<<dim3(NSP / 32, 8, NB), blk, 0, stream>>>(x, xT);
  gemm_mfma<0><<<dim3(NSP / 64, 12, NB), blk, 0, stream>>>(
      wbf, xT, qkT, vbuf, nullptr, nullptr, NSP);
  attn_mfma<<<dim3(NSP / 64, 8, NB), blk, 0, stream>>>(qkT, vbuf, attnoT);
  gemm_mfma<1><<<dim3(NSP / 64, 4, NB), blk, 0, stream>>>(
      wbf + 196608, attnoT, nullptr, nullptr, out, b_out, NSP);
}

// Round 6
// 96.987 us; speedup vs baseline: 2.2363x; 2.2363x over previous
//
#include <hip/hip_runtime.h>
#include <hip/hip_bf16.h>

#define NSP 2304   // 48*48 spatial
#define NB  4      // batch

typedef unsigned short u16;
typedef __attribute__((ext_vector_type(8))) short short8;
typedef __attribute__((ext_vector_type(4))) float f32x4;
typedef __attribute__((ext_vector_type(4))) unsigned short u16x4;

// scale * log2(e), folded into Q at QKV-GEMM epilogue: softmax p = exp2(S)
#define K1S 0.25508040852656425f

static __device__ inline u16 f2bf(float f) {
  return __builtin_bit_cast(unsigned short, __float2bfloat16(f));
}

// ---------------------------------------------------------------------------
// prep 1: w_qkv (768*256) and w_out (256*256) fp32 -> bf16, one region.
// ---------------------------------------------------------------------------
__global__ __launch_bounds__(256) void convert_w(
    const float* __restrict__ wq, const float* __restrict__ wo,
    u16* __restrict__ dst) {
  int i = (blockIdx.x * 256 + threadIdx.x) * 4;
  float4 v;
  if (i < 196608) v = *(const float4*)(wq + i);
  else            v = *(const float4*)(wo + (i - 196608));
  u16x4 p = {f2bf(v.x), f2bf(v.y), f2bf(v.z), f2bf(v.w)};
  *(u16x4*)(dst + i) = p;
}

// ---------------------------------------------------------------------------
// prep 2: x fp32 [b][256][2304] -> xT bf16 [b][2304][256]
// ---------------------------------------------------------------------------
__global__ __launch_bounds__(256) void transpose_x(
    const float* __restrict__ x, u16* __restrict__ xT) {
  __shared__ float tile[32][33];
  const int t = threadIdx.x;
  const int n0 = blockIdx.x * 32, c0 = blockIdx.y * 32, b = blockIdx.z;
  const float* xb = x + ((size_t)b * 256 + c0) * NSP + n0;
#pragma unroll
  for (int e = t; e < 1024; e += 256) {
    int cc = e >> 5, nn = e & 31;
    tile[cc][nn] = xb[(size_t)cc * NSP + nn];
  }
  __syncthreads();
  u16* xTb = xT + ((size_t)b * NSP + n0) * 256 + c0;
#pragma unroll
  for (int e = t; e < 1024; e += 256) {
    int nn = e >> 5, cc = e & 31;
    xTb[(size_t)nn * 256 + cc] = f2bf(tile[cc][nn]);
  }
}

// ---------------------------------------------------------------------------
// bf16 MFMA GEMM (LDS-staged, round-4 structure): D = A (Mx256) * B[b](Nx256)^T
// 64x64 tile, 4 waves (2x2 of 32x32), whole K=256 staged once.
// EPI 0: rows <256 q (pre-scaled K1S), 256..511 k -> qkT[b][n][512] bf16;
//        rows >=512 v -> vbuf[b][256][2304] bf16.
// EPI 1: fp32 out + bias.
// ---------------------------------------------------------------------------
template <int EPI>
__global__ __launch_bounds__(256) void gemm_mfma(
    const u16* __restrict__ A, const u16* __restrict__ B,
    u16* __restrict__ qkT, u16* __restrict__ vbuf,
    float* __restrict__ outf, const float* __restrict__ bias, int N) {
  __shared__ u16 As[64][264];
  __shared__ u16 Bs[64][264];
  const int t = threadIdx.x, lane = t & 63, wid = t >> 6;
  const int lo = lane & 15, g = lane >> 4;
  const int wr = wid >> 1, wc = wid & 1;
  const int row0 = blockIdx.y * 64, col0 = blockIdx.x * 64, b = blockIdx.z;

  const int sr = t >> 2, c4 = t & 3;
  const u16* Arow = A + (size_t)(row0 + sr) * 256;
  const u16* Brow = B + ((size_t)b * N + col0 + sr) * 256;
#pragma unroll
  for (int i = 0; i < 8; ++i) {
    int col = (c4 + 4 * i) * 8;
    *(uint4*)&As[sr][col] = *(const uint4*)&Arow[col];
    *(uint4*)&Bs[sr][col] = *(const uint4*)&Brow[col];
  }
  __syncthreads();

  f32x4 acc[2][2];
#pragma unroll
  for (int i = 0; i < 2; ++i)
#pragma unroll
    for (int j = 0; j < 2; ++j) acc[i][j] = (f32x4){0, 0, 0, 0};

  const int ar0 = wr * 32 + lo, br0 = wc * 32 + lo;
#pragma unroll
  for (int kk = 0; kk < 8; ++kk) {
    int kc = kk * 32 + g * 8;
    short8 a0 = *(const short8*)&As[ar0][kc];
    short8 a1 = *(const short8*)&As[ar0 + 16][kc];
    short8 b0 = *(const short8*)&Bs[br0][kc];
    short8 b1 = *(const short8*)&Bs[br0 + 16][kc];
    acc[0][0] = __builtin_amdgcn_mfma_f32_16x16x32_bf16(a0, b0, acc[0][0], 0, 0, 0);
    acc[0][1] = __builtin_amdgcn_mfma_f32_16x16x32_bf16(a0, b1, acc[0][1], 0, 0, 0);
    acc[1][0] = __builtin_amdgcn_mfma_f32_16x16x32_bf16(a1, b0, acc[1][0], 0, 0, 0);
    acc[1][1] = __builtin_amdgcn_mfma_f32_16x16x32_bf16(a1, b1, acc[1][1], 0, 0, 0);
  }

  const float qs = (EPI == 0 && row0 < 256) ? K1S : 1.0f;
#pragma unroll
  for (int m2 = 0; m2 < 2; ++m2)
#pragma unroll
    for (int n2 = 0; n2 < 2; ++n2) {
      int m = row0 + wr * 32 + m2 * 16 + g * 4;
      int n = col0 + wc * 32 + n2 * 16 + lo;
      if constexpr (EPI == 0) {
        if (row0 < 512) {  // q,k -> transposed qkT[b][n][m..m+3]
          u16x4 pk = {f2bf(acc[m2][n2][0] * qs), f2bf(acc[m2][n2][1] * qs),
                      f2bf(acc[m2][n2][2] * qs), f2bf(acc[m2][n2][3] * qs)};
          *(u16x4*)(qkT + ((size_t)b * NSP + n) * 512 + m) = pk;
        } else {           // v -> natural vbuf[b][m-512][n]
#pragma unroll
          for (int r = 0; r < 4; ++r)
            vbuf[((size_t)b * 256 + (m - 512 + r)) * NSP + n] =
                f2bf(acc[m2][n2][r]);
        }
      } else {
#pragma unroll
        for (int r = 0; r < 4; ++r)
          outf[((size_t)b * 256 + m + r) * NSP + n] =
              acc[m2][n2][r] + bias[m + r];
      }
    }
}

// ---------------------------------------------------------------------------
// MFMA flash attention: round-4 pipeline (reg-prefetch -> double-buffered LDS
// K/V, 1 barrier/strip) + round-5 softmax (p = exp2(S), scale pre-folded into
// Q, no max tracking, row-sum l via ones-MFMA, no cross-lane reduces).
// ---------------------------------------------------------------------------
__global__ __launch_bounds__(256) void attn_mfma(
    const u16* __restrict__ qkT, const u16* __restrict__ vbuf,
    u16* __restrict__ attnoT) {
  const int it = blockIdx.x, h = blockIdx.y, b = blockIdx.z;
  const int t = threadIdx.x, lane = t & 63, wq = t >> 6;
  const int lo = lane & 15, g = lane >> 4;
  const int i0 = it * 64;

  const u16* qkTb = qkT + (size_t)b * NSP * 512;
  const u16* vb   = vbuf + ((size_t)b * 256 + h * 32) * NSP;
  u16* ob = attnoT + ((size_t)b * NSP + i0) * 256 + h * 32;

  __shared__ u16 Kt[2][64][40];   // [j][d], stride 40: frag reads conflict-free
  __shared__ u16 Vs[2][32][72];   // [d][j]
  __shared__ u16 Ps[4][16][68];   // per-wave P, stride 68: 0 conflicts (r5)

  // Q fragment (pre-scaled by K1S in the QKV GEMM)
  short8 qf = *(const short8*)(qkTb + (size_t)(i0 + wq * 16 + lo) * 512 +
                               h * 32 + g * 8);

  // staging addresses (one b128 per thread per buffer)
  const int kr = t >> 2, kp = (t & 3) * 8;   // K: row j (64), d-part
  const int vr = t >> 3, vp = (t & 7) * 8;   // V: row d (32), j-part
  const u16* ksrc = qkTb + 256 + h * 32 + kp;           // + j*512
  const u16* vsrc = vb + (size_t)vr * NSP + vp;         // + j0

  uint4 kreg = *(const uint4*)(ksrc + (size_t)kr * 512);
  uint4 vreg = *(const uint4*)(vsrc);
  *(uint4*)&Kt[0][kr][kp] = kreg;
  *(uint4*)&Vs[0][vr][vp] = vreg;
  __syncthreads();

  short8 ones;
#pragma unroll
  for (int e = 0; e < 8; ++e) ones[e] = (short)0x3F80;  // bf16 1.0

  f32x4 acc0 = {0, 0, 0, 0}, acc1 = {0, 0, 0, 0}, accl = {0, 0, 0, 0};

  for (int s = 0; s < 36; ++s) {
    const int cur = s & 1;
    if (s + 1 < 36) {  // prefetch next strip into regs (hidden under compute)
      int j0n = (s + 1) * 64;
      kreg = *(const uint4*)(ksrc + (size_t)(j0n + kr) * 512);
      vreg = *(const uint4*)(vsrc + j0n);
    }

    // ---- S = Q K^T ----
    f32x4 sv[4];
#pragma unroll
    for (int jt = 0; jt < 4; ++jt) {
      short8 kf = *(const short8*)&Kt[cur][jt * 16 + lo][g * 8];
      sv[jt] = __builtin_amdgcn_mfma_f32_16x16x32_bf16(
          qf, kf, (f32x4){0, 0, 0, 0}, 0, 0, 0);
    }

    // ---- p = exp2(S) -> per-wave LDS ----
#pragma unroll
    for (int jt = 0; jt < 4; ++jt)
#pragma unroll
      for (int r = 0; r < 4; ++r)
        Ps[wq][g * 4 + r][jt * 16 + lo] =
            f2bf(__builtin_amdgcn_exp2f(sv[jt][r]));

    // ---- PV + row-sum l (all MFMA) ----
    short8 pf0 = *(const short8*)&Ps[wq][lo][g * 8];
    short8 pf1 = *(const short8*)&Ps[wq][lo][32 + g * 8];
    short8 vf00 = *(const short8*)&Vs[cur][lo][g * 8];
    short8 vf01 = *(const short8*)&Vs[cur][lo][32 + g * 8];
    short8 vf10 = *(const short8*)&Vs[cur][16 + lo][g * 8];
    short8 vf11 = *(const short8*)&Vs[cur][16 + lo][32 + g * 8];
    acc0 = __builtin_amdgcn_mfma_f32_16x16x32_bf16(pf0, vf00, acc0, 0, 0, 0);
    acc1 = __builtin_amdgcn_mfma_f32_16x16x32_bf16(pf0, vf10, acc1, 0, 0, 0);
    accl = __builtin_amdgcn_mfma_f32_16x16x32_bf16(pf0, ones, accl, 0, 0, 0);
    acc0 = __builtin_amdgcn_mfma_f32_16x16x32_bf16(pf1, vf01, acc0, 0, 0, 0);
    acc1 = __builtin_amdgcn_mfma_f32_16x16x32_bf16(pf1, vf11, acc1, 0, 0, 0);
    accl = __builtin_amdgcn_mfma_f32_16x16x32_bf16(pf1, ones, accl, 0, 0, 0);

    if (s + 1 < 36) {  // write next strip into the other buffer
      *(uint4*)&Kt[cur ^ 1][kr][kp] = kreg;
      *(uint4*)&Vs[cur ^ 1][vr][vp] = vreg;
    }
    __syncthreads();
  }

  // ---- normalize + bf16 store to attnoT[n][c] ----
#pragma unroll
  for (int r = 0; r < 4; ++r) {
    float inv = 1.0f / accl[r];
    int row = wq * 16 + g * 4 + r;
    ob[(size_t)row * 256 + lo]      = f2bf(acc0[r] * inv);
    ob[(size_t)row * 256 + 16 + lo] = f2bf(acc1[r] * inv);
  }
}

// ---------------------------------------------------------------------------
extern "C" void kernel_launch(void* const* d_in, const int* in_sizes, int n_in,
                              void* d_out, int out_size, void* d_ws, size_t ws_size,
                              hipStream_t stream) {
  const float* x     = (const float*)d_in[0];  // [4][256][48][48]
  const float* w_qkv = (const float*)d_in[1];  // [768][256]
  const float* w_out = (const float*)d_in[2];  // [256][256]
  const float* b_out = (const float*)d_in[3];  // [256]
  float* out = (float*)d_out;                  // [4][256][2304]

  u16* wbf    = (u16*)d_ws;                    // wqkv 196608 then wout 65536
  u16* xT     = wbf + 262144;                  // [4][2304][256]
  u16* qkT    = xT + (size_t)NB * NSP * 256;   // [4][2304][512]
  u16* vbuf   = qkT + (size_t)NB * NSP * 512;  // [4][256][2304]
  u16* attnoT = vbuf + (size_t)NB * 256 * NSP; // [4][2304][256]

  dim3 blk(256);
  convert_w<<<256, blk, 0, stream>>>(w_qkv, w_out, wbf);
  transpose_x<<<dim3(NSP / 32, 8, NB), blk, 0, stream>>>(x, xT);
  gemm_mfma<0><<<dim3(NSP / 64, 12, NB), blk, 0, stream>>>(
      wbf, xT, qkT, vbuf, nullptr, nullptr, NSP);
  attn_mfma<<<dim3(NSP / 64, 8, NB), blk, 0, stream>>>(qkT, vbuf, attnoT);
  gemm_mfma<1><<<dim3(NSP / 64, 4, NB), blk, 0, stream>>>(
      wbf + 196608, attnoT, nullptr, nullptr, out, b_out, NSP);
}